// Round 4
// baseline (301.974 us; speedup 1.0000x reference)
//
#include <hip/hip_runtime.h>
#include <hip/hip_cooperative_groups.h>

namespace cg = cooperative_groups;

#define NSEG 8
#define LSEG 32768
#define EPS_GN 1e-5f
#define KSCALE 0.005524271728019903f   // 1/sqrt(32768)
#define QSCALE 0.17677669529663687f    // 1/sqrt(32)
#define INVN 2.384185791015625e-07f    // 1/4194304

typedef __attribute__((ext_vector_type(4))) float f32x4;
typedef __attribute__((ext_vector_type(8))) __bf16 bf16x8;
typedef __attribute__((ext_vector_type(4))) short s16x4;

#define MFMA32(A, B, C) __builtin_amdgcn_mfma_f32_16x16x32_bf16(A, B, C, 0, 0, 0)
#define MFMA16(A, B, C) __builtin_amdgcn_mfma_f32_16x16x16bf16_1k(A, B, C, 0, 0, 0)

static __device__ __forceinline__ unsigned short f2bf(float f) {
  unsigned int u = __float_as_uint(f);
  u += 0x7fffu + ((u >> 16) & 1u);
  return (unsigned short)(u >> 16);
}
static __device__ __forceinline__ float bf2f(unsigned short s) {
  return __uint_as_float(((unsigned int)s) << 16);
}
static __device__ __forceinline__ s16x4 pack4(float a, float b, float c, float d) {
  union { __bf16 h[4]; s16x4 s; } u;
  u.h[0] = (__bf16)a; u.h[1] = (__bf16)b; u.h[2] = (__bf16)c; u.h[3] = (__bf16)d;
  return u.s;
}
static __device__ __forceinline__ uint2 packo(f32x4 v) {
  union { unsigned short h[4]; uint2 u; } z;
  z.h[0] = f2bf(v[0]); z.h[1] = f2bf(v[1]); z.h[2] = f2bf(v[2]); z.h[3] = f2bf(v[3]);
  return z.u;
}

// ---- fused: GN1 partial stats + x->bf16 copy (blocks 0..511) | W_qkv -> WT bf16 transposed (512..703)
__global__ __launch_bounds__(256) void k_pre(
    const float* __restrict__ x, float* __restrict__ part, unsigned short* __restrict__ xb,
    const float* __restrict__ W, const float* __restrict__ gn1w, unsigned short* __restrict__ WT)
{
  const int t = threadIdx.x;
  if (blockIdx.x >= 512) {
    int idx = (blockIdx.x - 512) * 256 + t;   // 49152 total
    int n = idx >> 7, ch = idx & 127;
    WT[idx] = f2bf(gn1w[ch] * W[ch * 384 + n]);
    return;
  }
  const int c = blockIdx.x;
  const float4* xp = (const float4*)x + (size_t)c * 16384;
  ushort4* xo = (ushort4*)xb + (size_t)c * 16384;
  float s = 0.f, q = 0.f;
  for (int i = 0; i < 64; ++i) {
    float4 v = xp[t + i * 256];
    s += v.x + v.y + v.z + v.w;
    q += v.x*v.x + v.y*v.y + v.z*v.z + v.w*v.w;
    xo[t + i * 256] = make_ushort4(f2bf(v.x), f2bf(v.y), f2bf(v.z), f2bf(v.w));
  }
  #pragma unroll
  for (int o = 1; o < 64; o <<= 1) { s += __shfl_xor(s, o); q += __shfl_xor(q, o); }
  __shared__ float red[8];
  int wave = t >> 6, lane = t & 63;
  if (lane == 0) { red[wave*2] = s; red[wave*2+1] = q; }
  __syncthreads();
  if (t == 0) {
    part[c*2]   = red[0] + red[2] + red[4] + red[6];
    part[c*2+1] = red[1] + red[3] + red[5] + red[7];
  }
}

// ---- k,v GEMM + exp(k) -> sum_e, ctx += E^T@V. 256 thr = 4 waves = 4 heads. No q.
__global__ __launch_bounds__(256, 2) void k_kv(
    const unsigned short* __restrict__ xb, const unsigned short* __restrict__ WT,
    const float* __restrict__ Wqkv, const float* __restrict__ gn1w, const float* __restrict__ gn1b,
    const float* __restrict__ part, float* __restrict__ sume_p, float* __restrict__ ctx_p)
{
  __shared__ float sm[2];        // mu*rs, rs
  __shared__ float sb01[512];    // B0[128..384), B1[128..384)
  __shared__ float sbias[256];   // scaled k,v bias

  const int t = threadIdx.x;
  const int h = t >> 6, lane = t & 63;
  const int lm = lane & 15, lg = lane >> 4;
  const int bid = blockIdx.x;               // 512 = 8 seg * 64 sub
  const int seg = bid >> 6, sub = bid & 63;

  // stats1 finalize (seg-local)
  if (t < 64) {
    float s = part[(seg*64 + t)*2], q = part[(seg*64 + t)*2 + 1];
    #pragma unroll
    for (int o = 1; o < 64; o <<= 1) { s += __shfl_xor(s, o); q += __shfl_xor(q, o); }
    if (t == 0) {
      float mu = s * INVN;
      float var = q * INVN - mu * mu;
      float rs = rsqrtf(var + EPS_GN);
      sm[0] = mu * rs; sm[1] = rs;
    }
  }
  // B0/B1 for n in [128,384)
  for (int p = t; p < 512; p += 256) {
    int which = p >> 8, n = 128 + (p & 255);
    const float* gv = which ? gn1w : gn1b;
    float s = 0.f;
    for (int ch = 0; ch < 128; ++ch) s += gv[ch] * Wqkv[ch*384 + n];
    sb01[p] = s;
  }
  __syncthreads();
  {
    float mu_rs = sm[0];
    int p = t;  // 256 threads cover 256 n's
    float v = sb01[p] - mu_rs * sb01[256 + p];
    sbias[p] = v * ((p < 128) ? KSCALE : 1.f);
  }
  __syncthreads();

  const float rs = sm[1];
  const float alk = rs * KSCALE, alv = rs;
  const float ck0 = sbias[h*32 + lm],       ck1 = sbias[h*32 + 16 + lm];
  const float cv0 = sbias[128 + h*32 + lm], cv1 = sbias[128 + h*32 + 16 + lm];

  // register-resident W fragments
  bf16x8 wk[2][4], wv[2][4];
  #pragma unroll
  for (int nt = 0; nt < 2; ++nt)
    #pragma unroll
    for (int kk = 0; kk < 4; ++kk) {
      int row = h*32 + nt*16 + lm;
      wk[nt][kk] = *(const bf16x8*)&WT[(row + 128) * 128 + kk*32 + lg*8];
      wv[nt][kk] = *(const bf16x8*)&WT[(row + 256) * 128 + kk*32 + lg*8];
    }

  f32x4 ctx00 = {0,0,0,0}, ctx01 = {0,0,0,0}, ctx10 = {0,0,0,0}, ctx11 = {0,0,0,0};
  float se0 = 0.f, se1 = 0.f;

  const unsigned short* xw = xb + (size_t)(seg * LSEG + sub*512 + lm) * 128 + lg*8;

#define ISSUE(S, IT) { \
    const unsigned short* p_ = xw + (size_t)((IT) * 16) * 128; \
    S[0] = *(const bf16x8*)(p_);      \
    S[1] = *(const bf16x8*)(p_ + 32); \
    S[2] = *(const bf16x8*)(p_ + 64); \
    S[3] = *(const bf16x8*)(p_ + 96); }

#define COMPUTE(S) { \
    f32x4 ka0 = {0,0,0,0}, ka1 = {0,0,0,0}, va0 = {0,0,0,0}, va1 = {0,0,0,0}; \
    _Pragma("unroll") for (int kk = 0; kk < 4; ++kk) { \
      ka0 = MFMA32(S[kk], wk[0][kk], ka0); \
      ka1 = MFMA32(S[kk], wk[1][kk], ka1); \
    } \
    _Pragma("unroll") for (int kk = 0; kk < 4; ++kk) { \
      va0 = MFMA32(S[kk], wv[0][kk], va0); \
      va1 = MFMA32(S[kk], wv[1][kk], va1); \
    } \
    float e_[8]; \
    _Pragma("unroll") for (int r = 0; r < 4; ++r) { \
      e_[r]     = __expf(fmaf(ka0[r], alk, ck0)); \
      e_[4 + r] = __expf(fmaf(ka1[r], alk, ck1)); \
    } \
    se0 += (e_[0] + e_[1]) + (e_[2] + e_[3]); \
    se1 += (e_[4] + e_[5]) + (e_[6] + e_[7]); \
    s16x4 E0 = pack4(e_[0], e_[1], e_[2], e_[3]); \
    s16x4 E1 = pack4(e_[4], e_[5], e_[6], e_[7]); \
    s16x4 V0 = pack4(fmaf(va0[0], alv, cv0), fmaf(va0[1], alv, cv0), \
                     fmaf(va0[2], alv, cv0), fmaf(va0[3], alv, cv0)); \
    s16x4 V1 = pack4(fmaf(va1[0], alv, cv1), fmaf(va1[1], alv, cv1), \
                     fmaf(va1[2], alv, cv1), fmaf(va1[3], alv, cv1)); \
    ctx00 = MFMA16(E0, V0, ctx00); \
    ctx01 = MFMA16(E0, V1, ctx01); \
    ctx10 = MFMA16(E1, V0, ctx10); \
    ctx11 = MFMA16(E1, V1, ctx11); }

  bf16x8 sA[4], sB[4], sC[4], sD[4];
  ISSUE(sA, 0);
  ISSUE(sB, 1);
  #pragma unroll 1
  for (int it = 0; it < 32; it += 4) {
    ISSUE(sC, it + 2);
    COMPUTE(sA);
    ISSUE(sD, it + 3);
    COMPUTE(sB);
    if (it + 4 < 32) ISSUE(sA, it + 4);
    COMPUTE(sC);
    if (it + 5 < 32) ISSUE(sB, it + 5);
    COMPUTE(sD);
  }
#undef ISSUE
#undef COMPUTE

  se0 += __shfl_xor(se0, 16); se0 += __shfl_xor(se0, 32);
  se1 += __shfl_xor(se1, 16); se1 += __shfl_xor(se1, 32);
  if (lane < 16) {
    sume_p[(size_t)bid*128 + h*32 + lm]      = se0;
    sume_p[(size_t)bid*128 + h*32 + 16 + lm] = se1;
  }
  float* cp = ctx_p + (size_t)bid*4096 + h*1024;
  #pragma unroll
  for (int r = 0; r < 4; ++r) {
    cp[(lg*4 + r)*32      + lm]      = ctx00[r];
    cp[(lg*4 + r)*32      + 16 + lm] = ctx01[r];
    cp[(16 + lg*4 + r)*32 + lm]      = ctx10[r];
    cp[(16 + lg*4 + r)*32 + 16 + lm] = ctx11[r];
  }
}

// ---- reduce ctx partials, normalize, fold Wc = blockdiag(ctx)@W_out -> WcT[seg][oc][qc] bf16
// 256 blocks: (seg, head, oc-group of 16)
__global__ __launch_bounds__(256) void k_wc(
    const float* __restrict__ sume_p, const float* __restrict__ ctx_p,
    const float* __restrict__ Wout, unsigned short* __restrict__ WcT)
{
  __shared__ float sctx[1024];
  __shared__ float sse[32];
  const int t = threadIdx.x, b = blockIdx.x;
  const int seg = b >> 5, head = (b >> 3) & 3, ocg = b & 7;
  float acc[4] = {0.f, 0.f, 0.f, 0.f};
  for (int j = 0; j < 64; ++j) {
    const float* cp = ctx_p + (size_t)(seg*64 + j)*4096 + head*1024;
    #pragma unroll
    for (int e = 0; e < 4; ++e) acc[e] += cp[t + e*256];
  }
  if (t < 32) {
    float s = 0.f;
    for (int j = 0; j < 64; ++j) s += sume_p[(size_t)(seg*64 + j)*128 + head*32 + t];
    sse[t] = s;
  }
  #pragma unroll
  for (int e = 0; e < 4; ++e) sctx[t + e*256] = acc[e];
  __syncthreads();
  #pragma unroll
  for (int e = 0; e < 2; ++e) {
    int idx = t + e*256;              // 512 outputs: 32 kc x 16 oc
    int kc = idx >> 4, ocl = idx & 15;
    int oc = ocg*16 + ocl;
    float s = 0.f;
    #pragma unroll
    for (int vc = 0; vc < 32; ++vc)
      s += sctx[kc*32 + vc] * Wout[(head*32 + vc)*128 + oc];
    WcT[((size_t)seg*128 + oc)*128 + head*32 + kc] = f2bf(s / sse[kc]);
  }
}

// ---- q recompute -> softmax -> P LDS exchange -> out frags (regs) + stats2; [COOP] grid.sync;
//      normalize + residual + y.   512 blocks x 256 thr, chunk = 512 points.
template<bool COOP>
__global__ __launch_bounds__(256, 2) void k_out2(
    const unsigned short* __restrict__ xb, const unsigned short* __restrict__ WT,
    const float* __restrict__ Wqkv, const float* __restrict__ gn1w, const float* __restrict__ gn1b,
    const float* __restrict__ part, const unsigned short* __restrict__ WcT,
    const float* __restrict__ gn2w, const float* __restrict__ gn2b,
    float* __restrict__ part2, unsigned short* __restrict__ outm, float* __restrict__ y)
{
  __shared__ float sm[2];
  __shared__ float sb01[256];
  __shared__ float sbq[128];
  __shared__ float red[8];
  __shared__ float sm2[8][2];
  __shared__ float sgw[128], sgb[128];
  __shared__ __attribute__((aligned(16))) short pbuf[2][8 * 256];       // P exchange, dbuf
  __shared__ __attribute__((aligned(16))) float sOf[2][16 * 136];       // out staging, dbuf

  const int t = threadIdx.x;
  const int w = t >> 6, lane = t & 63;
  const int lm = lane & 15, lg = lane >> 4;
  const int bid = blockIdx.x;               // 512 = 8 seg * 64 sub
  const int seg = bid >> 6;
  const size_t cb = (size_t)bid * 512;      // chunk point base

  // ---- prologue: stats1 -> rs; q-bias fold; stage gn2
  if (t < 64) {
    float s = part[(seg*64 + t)*2], q = part[(seg*64 + t)*2 + 1];
    #pragma unroll
    for (int o = 1; o < 64; o <<= 1) { s += __shfl_xor(s, o); q += __shfl_xor(q, o); }
    if (t == 0) {
      float mu = s * INVN;
      float var = q * INVN - mu * mu;
      float rs = rsqrtf(var + EPS_GN);
      sm[0] = mu * rs; sm[1] = rs;
    }
  }
  for (int p = t; p < 256; p += 256) {
    int which = p >> 7, n = p & 127;
    const float* gv = which ? gn1w : gn1b;
    float s = 0.f;
    for (int ch = 0; ch < 128; ++ch) s += gv[ch] * Wqkv[ch*384 + n];
    sb01[p] = s;
  }
  if (t < 128) { sgw[t] = gn2w[t]; sgb[t] = gn2b[t]; }
  __syncthreads();
  if (t < 128) sbq[t] = (sb01[t] - sm[0] * sb01[128 + t]) * QSCALE;
  __syncthreads();

  const float alq = sm[1] * QSCALE;
  const float4 cq0 = *(const float4*)&sbq[w*32 + lg*4];
  const float4 cq1 = *(const float4*)&sbq[w*32 + 16 + lg*4];

  // register-resident Wq frags (head w) and Wc frags (this wave's 32 oc)
  bf16x8 wq[2][4];
  #pragma unroll
  for (int nt = 0; nt < 2; ++nt)
    #pragma unroll
    for (int kk = 0; kk < 4; ++kk)
      wq[nt][kk] = *(const bf16x8*)&WT[(w*32 + nt*16 + lm) * 128 + kk*32 + lg*8];
  s16x4 wc[2][8];
  #pragma unroll
  for (int o = 0; o < 2; ++o)
    #pragma unroll
    for (int kt = 0; kt < 8; ++kt)
      wc[o][kt] = *(const s16x4*)&WcT[((size_t)seg*128 + (w*32 + o*16 + lm))*128 + kt*16 + lg*4];

  const unsigned short* xw = xb + (cb + lm) * 128 + lg*8;
  uint2 oreg[32][2];
  float ssum = 0.f, ssq = 0.f;

  // ---- phase a: 32 tiles of 16 points
  #pragma unroll
  for (int ia = 0; ia < 32; ++ia) {
    const unsigned short* p_ = xw + (size_t)(ia * 16) * 128;
    bf16x8 xf0 = *(const bf16x8*)(p_);
    bf16x8 xf1 = *(const bf16x8*)(p_ + 32);
    bf16x8 xf2 = *(const bf16x8*)(p_ + 64);
    bf16x8 xf3 = *(const bf16x8*)(p_ + 96);
    f32x4 qa0 = {0,0,0,0}, qa1 = {0,0,0,0};
    qa0 = MFMA32(wq[0][0], xf0, qa0); qa1 = MFMA32(wq[1][0], xf0, qa1);
    qa0 = MFMA32(wq[0][1], xf1, qa0); qa1 = MFMA32(wq[1][1], xf1, qa1);
    qa0 = MFMA32(wq[0][2], xf2, qa0); qa1 = MFMA32(wq[1][2], xf2, qa1);
    qa0 = MFMA32(wq[0][3], xf3, qa0); qa1 = MFMA32(wq[1][3], xf3, qa1);
    float a[8];
    #pragma unroll
    for (int r = 0; r < 4; ++r) {
      a[r]     = fmaf(qa0[r], alq, ((const float*)&cq0)[r]);
      a[4 + r] = fmaf(qa1[r], alq, ((const float*)&cq1)[r]);
    }
    float m = a[0];
    #pragma unroll
    for (int i = 1; i < 8; ++i) m = fmaxf(m, a[i]);
    m = fmaxf(m, __shfl_xor(m, 16));
    m = fmaxf(m, __shfl_xor(m, 32));
    float s = 0.f;
    #pragma unroll
    for (int i = 0; i < 8; ++i) { a[i] = __expf(a[i] - m); s += a[i]; }
    s += __shfl_xor(s, 16);
    s += __shfl_xor(s, 32);
    float inv = 1.f / s;
    *(s16x4*)&pbuf[ia & 1][(w*2)*256 + lane*4]     = pack4(a[0]*inv, a[1]*inv, a[2]*inv, a[3]*inv);
    *(s16x4*)&pbuf[ia & 1][(w*2 + 1)*256 + lane*4] = pack4(a[4]*inv, a[5]*inv, a[6]*inv, a[7]*inv);
    __syncthreads();
    f32x4 acc0 = {0,0,0,0}, acc1 = {0,0,0,0};
    #pragma unroll
    for (int kt = 0; kt < 8; ++kt) {
      s16x4 pk = *(const s16x4*)&pbuf[ia & 1][kt*256 + lane*4];
      acc0 = MFMA16(wc[0][kt], pk, acc0);
      acc1 = MFMA16(wc[1][kt], pk, acc1);
    }
    #pragma unroll
    for (int r = 0; r < 4; ++r) {
      ssum += acc0[r] + acc1[r];
      ssq  += acc0[r]*acc0[r] + acc1[r]*acc1[r];
    }
    if constexpr (COOP) {
      oreg[ia][0] = packo(acc0);
      oreg[ia][1] = packo(acc1);
    } else {
      // OUTMEM: stage bf16 rows and store linear out
      unsigned short* sou = (unsigned short*)&sOf[0][0];  // reuse as ushort [16][272]
      uint2 v0 = packo(acc0), v1 = packo(acc1);
      unsigned short* dst = &sou[lm*272 + w*32 + lg*4];
      dst[0] = (unsigned short)(v0.x & 0xffff); dst[1] = (unsigned short)(v0.x >> 16);
      dst[2] = (unsigned short)(v0.y & 0xffff); dst[3] = (unsigned short)(v0.y >> 16);
      dst += 16;
      dst[0] = (unsigned short)(v1.x & 0xffff); dst[1] = (unsigned short)(v1.x >> 16);
      dst[2] = (unsigned short)(v1.y & 0xffff); dst[3] = (unsigned short)(v1.y >> 16);
      __syncthreads();
      #pragma unroll
      for (int j = 0; j < 2; ++j) {
        int f = t + j*256;
        int pt = f >> 5, cc = f & 31;
        ((ushort4*)outm)[(cb + (size_t)ia*16 + pt)*32 + cc] = *(const ushort4*)&sou[pt*272 + cc*4];
      }
      __syncthreads();
    }
  }

  // stats2 partials
  #pragma unroll
  for (int o = 1; o < 64; o <<= 1) { ssum += __shfl_xor(ssum, o); ssq += __shfl_xor(ssq, o); }
  if (lane == 0) { red[w*2] = ssum; red[w*2+1] = ssq; }
  __syncthreads();
  if (t == 0) {
    part2[bid*2]   = red[0] + red[2] + red[4] + red[6];
    part2[bid*2+1] = red[1] + red[3] + red[5] + red[7];
  }

  if constexpr (!COOP) return;

  __threadfence();
  cg::this_grid().sync();

  // ---- phase b: stats2 finalize + normalize + residual + y
  {
    int l = t & 63;
    for (int sseg = w; sseg < 8; sseg += 4) {
      float s = part2[(sseg*64 + l)*2], q = part2[(sseg*64 + l)*2 + 1];
      #pragma unroll
      for (int o = 1; o < 64; o <<= 1) { s += __shfl_xor(s, o); q += __shfl_xor(q, o); }
      if (l == 0) {
        float mu = s * INVN;
        float var = q * INVN - mu * mu;
        sm2[sseg][0] = mu; sm2[sseg][1] = rsqrtf(var + EPS_GN);
      }
    }
  }
  __syncthreads();
  const float mu2 = sm2[seg][0], rs2 = sm2[seg][1];
  const int c4 = t & 31;
  const float4 w4 = *(const float4*)&sgw[c4*4];
  const float4 g4 = *(const float4*)&sgb[c4*4];
  const ushort4* xb4 = (const ushort4*)xb;
  float4* y4 = (float4*)y;

  #pragma unroll
  for (int ia = 0; ia < 32; ++ia) {
    float* so = &sOf[ia & 1][0];
    {
      uint2 v0 = oreg[ia][0], v1 = oreg[ia][1];
      float* dst = &so[lm*136 + w*32 + lg*4];
      dst[0] = bf2f((unsigned short)(v0.x & 0xffff));
      dst[1] = bf2f((unsigned short)(v0.x >> 16));
      dst[2] = bf2f((unsigned short)(v0.y & 0xffff));
      dst[3] = bf2f((unsigned short)(v0.y >> 16));
      dst += 16;
      dst[0] = bf2f((unsigned short)(v1.x & 0xffff));
      dst[1] = bf2f((unsigned short)(v1.x >> 16));
      dst[2] = bf2f((unsigned short)(v1.y & 0xffff));
      dst[3] = bf2f((unsigned short)(v1.y >> 16));
    }
    __syncthreads();
    #pragma unroll
    for (int j = 0; j < 2; ++j) {
      int f = t + j*256;
      int pt = f >> 5, cc = f & 31;
      float4 ov = *(const float4*)&so[pt*136 + cc*4];
      ushort4 xv = xb4[(cb + (size_t)ia*16 + pt)*32 + cc];
      float4 r;
      r.x = (ov.x - mu2) * rs2 * w4.x + g4.x + bf2f(xv.x);
      r.y = (ov.y - mu2) * rs2 * w4.y + g4.y + bf2f(xv.y);
      r.z = (ov.z - mu2) * rs2 * w4.z + g4.z + bf2f(xv.z);
      r.w = (ov.w - mu2) * rs2 * w4.w + g4.w + bf2f(xv.w);
      y4[(cb + (size_t)ia*16 + pt)*32 + cc] = r;
    }
  }
}

// ---- fallback final: GN2 (stats from part2[512]) + residual
__global__ __launch_bounds__(256) void k_final_old(
    const unsigned short* __restrict__ xb, const unsigned short* __restrict__ out_ws,
    const float* __restrict__ part2, const float* __restrict__ gn2w, const float* __restrict__ gn2b,
    float* __restrict__ y)
{
  __shared__ float sm[2];
  const int t = threadIdx.x;
  const int b = blockIdx.x >> 8, blk = blockIdx.x & 255;
  if (t < 64) {
    float s = part2[(b*64 + t)*2], q = part2[(b*64 + t)*2 + 1];
    #pragma unroll
    for (int o = 1; o < 64; o <<= 1) { s += __shfl_xor(s, o); q += __shfl_xor(q, o); }
    if (t == 0) {
      float mu = s * INVN;
      float var = q * INVN - mu * mu;
      sm[0] = mu; sm[1] = rsqrtf(var + EPS_GN);
    }
  }
  __syncthreads();
  const float mu = sm[0], rs = sm[1];
  const int c4 = t & 31;
  const float4 w4 = *(const float4*)&gn2w[c4*4];
  const float4 g4 = *(const float4*)&gn2b[c4*4];
  const size_t base = (size_t)b * 1048576 + (size_t)blk * 4096;
  const ushort4* xp = (const ushort4*)xb + base;
  const ushort4* op = (const ushort4*)out_ws + base;
  float4* yp = (float4*)y + base;
  #pragma unroll
  for (int i = 0; i < 16; ++i) {
    int f = t + i * 256;
    ushort4 xv = xp[f];
    ushort4 ov = op[f];
    float4 r;
    r.x = (bf2f(ov.x) - mu) * rs * w4.x + g4.x + bf2f(xv.x);
    r.y = (bf2f(ov.y) - mu) * rs * w4.y + g4.y + bf2f(xv.y);
    r.z = (bf2f(ov.z) - mu) * rs * w4.z + g4.z + bf2f(xv.z);
    r.w = (bf2f(ov.w) - mu) * rs * w4.w + g4.w + bf2f(xv.w);
    yp[f] = r;
  }
}

extern "C" void kernel_launch(void* const* d_in, const int* in_sizes, int n_in,
                              void* d_out, int out_size, void* d_ws, size_t ws_size,
                              hipStream_t stream) {
  const float* x    = (const float*)d_in[0];
  const float* gn1w = (const float*)d_in[1];
  const float* gn1b = (const float*)d_in[2];
  const float* Wqkv = (const float*)d_in[3];
  const float* Wout = (const float*)d_in[4];
  const float* gn2w = (const float*)d_in[5];
  const float* gn2b = (const float*)d_in[6];
  float* y = (float*)d_out;
  char* ws = (char*)d_ws;

  float*          part   = (float*)(ws + 0);                 // 512*2 f32
  float*          part2  = (float*)(ws + 4096);              // 512*2 f32
  unsigned short* WT     = (unsigned short*)(ws + 8192);     // 384*128 bf16
  unsigned short* WcT    = (unsigned short*)(ws + 106496);   // 8*128*128 bf16 = 262144
  float*          sume_p = (float*)(ws + 368640);            // 512*128 f32 = 262144
  float*          ctx_p  = (float*)(ws + 630784);            // 512*4096 f32 = 8388608
  unsigned short* xb     = (unsigned short*)(ws + 9019392);  // 67108864
  unsigned short* outm   = (unsigned short*)(ws + 76128256); // 67108864 (fallback only)

  hipLaunchKernelGGL(k_pre, dim3(704), dim3(256), 0, stream, x, part, xb, Wqkv, gn1w, WT);
  hipLaunchKernelGGL(k_kv,  dim3(512), dim3(256), 0, stream, xb, WT, Wqkv, gn1w, gn1b, part, sume_p, ctx_p);
  hipLaunchKernelGGL(k_wc,  dim3(256), dim3(256), 0, stream, sume_p, ctx_p, Wout, WcT);

  const unsigned short* xb_c  = xb;
  const unsigned short* WT_c  = WT;
  const unsigned short* WcT_c = WcT;
  const float* part_c = part;
  void* args[] = {
    (void*)&xb_c, (void*)&WT_c, (void*)&Wqkv, (void*)&gn1w, (void*)&gn1b,
    (void*)&part_c, (void*)&WcT_c, (void*)&gn2w, (void*)&gn2b,
    (void*)&part2, (void*)&outm, (void*)&y
  };
  hipError_t ce = hipLaunchCooperativeKernel((void*)k_out2<true>, dim3(512), dim3(256),
                                             args, 0, stream);
  if (ce != hipSuccess) {
    hipLaunchKernelGGL((k_out2<false>), dim3(512), dim3(256), 0, stream,
                       xb, WT, Wqkv, gn1w, gn1b, part, WcT, gn2w, gn2b, part2, outm, y);
    hipLaunchKernelGGL(k_final_old, dim3(2048), dim3(256), 0, stream,
                       xb, outm, part2, gn2w, gn2b, y);
  }
}

// Round 5
// 213.910 us; speedup vs baseline: 1.4117x; 1.4117x over previous
//
#include <hip/hip_runtime.h>

#define NSEG 8
#define LSEG 32768
#define EPS_GN 1e-5f
#define KSCALE 0.005524271728019903f   // 1/sqrt(32768)
#define QSCALE 0.17677669529663687f    // 1/sqrt(32)
#define INVN 2.384185791015625e-07f    // 1/4194304

typedef __attribute__((ext_vector_type(4))) float f32x4;
typedef __attribute__((ext_vector_type(8))) __bf16 bf16x8;
typedef __attribute__((ext_vector_type(4))) short s16x4;

#define MFMA32(A, B, C) __builtin_amdgcn_mfma_f32_16x16x32_bf16(A, B, C, 0, 0, 0)
#define MFMA16(A, B, C) __builtin_amdgcn_mfma_f32_16x16x16bf16_1k(A, B, C, 0, 0, 0)

static __device__ __forceinline__ unsigned short f2bf(float f) {
  unsigned int u = __float_as_uint(f);
  u += 0x7fffu + ((u >> 16) & 1u);
  return (unsigned short)(u >> 16);
}
static __device__ __forceinline__ float bf2f(unsigned short s) {
  return __uint_as_float(((unsigned int)s) << 16);
}
static __device__ __forceinline__ s16x4 pack4(float a, float b, float c, float d) {
  union { __bf16 h[4]; s16x4 s; } u;
  u.h[0] = (__bf16)a; u.h[1] = (__bf16)b; u.h[2] = (__bf16)c; u.h[3] = (__bf16)d;
  return u.s;
}

// ---- fused: GN1 partial stats + x->bf16 copy (blocks 0..511) | W_qkv -> WT bf16 transposed (512..703)
__global__ __launch_bounds__(256) void k_pre(
    const float* __restrict__ x, float* __restrict__ part, unsigned short* __restrict__ xb,
    const float* __restrict__ W, const float* __restrict__ gn1w, unsigned short* __restrict__ WT)
{
  const int t = threadIdx.x;
  if (blockIdx.x >= 512) {
    int idx = (blockIdx.x - 512) * 256 + t;   // 49152 total
    int n = idx >> 7, ch = idx & 127;
    WT[idx] = f2bf(gn1w[ch] * W[ch * 384 + n]);
    return;
  }
  const int c = blockIdx.x;
  const float4* xp = (const float4*)x + (size_t)c * 16384;
  ushort4* xo = (ushort4*)xb + (size_t)c * 16384;
  float s = 0.f, q = 0.f;
  for (int i = 0; i < 64; ++i) {
    float4 v = xp[t + i * 256];
    s += v.x + v.y + v.z + v.w;
    q += v.x*v.x + v.y*v.y + v.z*v.z + v.w*v.w;
    xo[t + i * 256] = make_ushort4(f2bf(v.x), f2bf(v.y), f2bf(v.z), f2bf(v.w));
  }
  #pragma unroll
  for (int o = 1; o < 64; o <<= 1) { s += __shfl_xor(s, o); q += __shfl_xor(q, o); }
  __shared__ float red[8];
  int wave = t >> 6, lane = t & 63;
  if (lane == 0) { red[wave*2] = s; red[wave*2+1] = q; }
  __syncthreads();
  if (t == 0) {
    part[c*2]   = red[0] + red[2] + red[4] + red[6];
    part[c*2+1] = red[1] + red[3] + red[5] + red[7];
  }
}

// ---- k,v GEMM + exp(k) -> sum_e, ctx += E^T@V. 256 thr = 4 waves = 4 heads.
__global__ __launch_bounds__(256, 2) void k_kv(
    const unsigned short* __restrict__ xb, const unsigned short* __restrict__ WT,
    const float* __restrict__ Wqkv, const float* __restrict__ gn1w, const float* __restrict__ gn1b,
    const float* __restrict__ part, float* __restrict__ sume_p, float* __restrict__ ctx_p)
{
  __shared__ float sm[2];        // mu*rs, rs
  __shared__ float sb01[512];    // B0[128..384), B1[128..384)
  __shared__ float sbias[256];   // scaled k,v bias

  const int t = threadIdx.x;
  const int h = t >> 6, lane = t & 63;
  const int lm = lane & 15, lg = lane >> 4;
  const int bid = blockIdx.x;               // 512 = 8 seg * 64 sub
  const int seg = bid >> 6, sub = bid & 63;

  if (t < 64) {
    float s = part[(seg*64 + t)*2], q = part[(seg*64 + t)*2 + 1];
    #pragma unroll
    for (int o = 1; o < 64; o <<= 1) { s += __shfl_xor(s, o); q += __shfl_xor(q, o); }
    if (t == 0) {
      float mu = s * INVN;
      float var = q * INVN - mu * mu;
      float rs = rsqrtf(var + EPS_GN);
      sm[0] = mu * rs; sm[1] = rs;
    }
  }
  for (int p = t; p < 512; p += 256) {
    int which = p >> 8, n = 128 + (p & 255);
    const float* gv = which ? gn1w : gn1b;
    float s = 0.f;
    for (int ch = 0; ch < 128; ++ch) s += gv[ch] * Wqkv[ch*384 + n];
    sb01[p] = s;
  }
  __syncthreads();
  {
    float mu_rs = sm[0];
    int p = t;
    float v = sb01[p] - mu_rs * sb01[256 + p];
    sbias[p] = v * ((p < 128) ? KSCALE : 1.f);
  }
  __syncthreads();

  const float rs = sm[1];
  const float alk = rs * KSCALE, alv = rs;
  const float ck0 = sbias[h*32 + lm],       ck1 = sbias[h*32 + 16 + lm];
  const float cv0 = sbias[128 + h*32 + lm], cv1 = sbias[128 + h*32 + 16 + lm];

  bf16x8 wk[2][4], wv[2][4];
  #pragma unroll
  for (int nt = 0; nt < 2; ++nt)
    #pragma unroll
    for (int kk = 0; kk < 4; ++kk) {
      int row = h*32 + nt*16 + lm;
      wk[nt][kk] = *(const bf16x8*)&WT[(row + 128) * 128 + kk*32 + lg*8];
      wv[nt][kk] = *(const bf16x8*)&WT[(row + 256) * 128 + kk*32 + lg*8];
    }

  f32x4 ctx00 = {0,0,0,0}, ctx01 = {0,0,0,0}, ctx10 = {0,0,0,0}, ctx11 = {0,0,0,0};
  float se0 = 0.f, se1 = 0.f;

  const unsigned short* xw = xb + (size_t)(seg * LSEG + sub*512 + lm) * 128 + lg*8;

#define ISSUE(S, IT) { \
    const unsigned short* p_ = xw + (size_t)((IT) * 16) * 128; \
    S[0] = *(const bf16x8*)(p_);      \
    S[1] = *(const bf16x8*)(p_ + 32); \
    S[2] = *(const bf16x8*)(p_ + 64); \
    S[3] = *(const bf16x8*)(p_ + 96); }

#define COMPUTE(S) { \
    f32x4 ka0 = {0,0,0,0}, ka1 = {0,0,0,0}, va0 = {0,0,0,0}, va1 = {0,0,0,0}; \
    _Pragma("unroll") for (int kk = 0; kk < 4; ++kk) { \
      ka0 = MFMA32(S[kk], wk[0][kk], ka0); \
      ka1 = MFMA32(S[kk], wk[1][kk], ka1); \
    } \
    _Pragma("unroll") for (int kk = 0; kk < 4; ++kk) { \
      va0 = MFMA32(S[kk], wv[0][kk], va0); \
      va1 = MFMA32(S[kk], wv[1][kk], va1); \
    } \
    float e_[8]; \
    _Pragma("unroll") for (int r = 0; r < 4; ++r) { \
      e_[r]     = __expf(fmaf(ka0[r], alk, ck0)); \
      e_[4 + r] = __expf(fmaf(ka1[r], alk, ck1)); \
    } \
    se0 += (e_[0] + e_[1]) + (e_[2] + e_[3]); \
    se1 += (e_[4] + e_[5]) + (e_[6] + e_[7]); \
    s16x4 E0 = pack4(e_[0], e_[1], e_[2], e_[3]); \
    s16x4 E1 = pack4(e_[4], e_[5], e_[6], e_[7]); \
    s16x4 V0 = pack4(fmaf(va0[0], alv, cv0), fmaf(va0[1], alv, cv0), \
                     fmaf(va0[2], alv, cv0), fmaf(va0[3], alv, cv0)); \
    s16x4 V1 = pack4(fmaf(va1[0], alv, cv1), fmaf(va1[1], alv, cv1), \
                     fmaf(va1[2], alv, cv1), fmaf(va1[3], alv, cv1)); \
    ctx00 = MFMA16(E0, V0, ctx00); \
    ctx01 = MFMA16(E0, V1, ctx01); \
    ctx10 = MFMA16(E1, V0, ctx10); \
    ctx11 = MFMA16(E1, V1, ctx11); }

  bf16x8 sA[4], sB[4], sC[4], sD[4];
  ISSUE(sA, 0);
  ISSUE(sB, 1);
  #pragma unroll 1
  for (int it = 0; it < 32; it += 4) {
    ISSUE(sC, it + 2);
    COMPUTE(sA);
    ISSUE(sD, it + 3);
    COMPUTE(sB);
    if (it + 4 < 32) ISSUE(sA, it + 4);
    COMPUTE(sC);
    if (it + 5 < 32) ISSUE(sB, it + 5);
    COMPUTE(sD);
  }
#undef ISSUE
#undef COMPUTE

  se0 += __shfl_xor(se0, 16); se0 += __shfl_xor(se0, 32);
  se1 += __shfl_xor(se1, 16); se1 += __shfl_xor(se1, 32);
  if (lane < 16) {
    sume_p[(size_t)bid*128 + h*32 + lm]      = se0;
    sume_p[(size_t)bid*128 + h*32 + 16 + lm] = se1;
  }
  float* cp = ctx_p + (size_t)bid*4096 + h*1024;
  #pragma unroll
  for (int r = 0; r < 4; ++r) {
    cp[(lg*4 + r)*32      + lm]      = ctx00[r];
    cp[(lg*4 + r)*32      + 16 + lm] = ctx01[r];
    cp[(16 + lg*4 + r)*32 + lm]      = ctx10[r];
    cp[(16 + lg*4 + r)*32 + 16 + lm] = ctx11[r];
  }
}

// ---- reduce ctx partials, normalize, fold Wc = blockdiag(ctx)@W_out -> WcT[seg][oc][qc] bf16
__global__ __launch_bounds__(256) void k_wc(
    const float* __restrict__ sume_p, const float* __restrict__ ctx_p,
    const float* __restrict__ Wout, unsigned short* __restrict__ WcT)
{
  __shared__ float sctx[1024];
  __shared__ float sse[32];
  const int t = threadIdx.x, b = blockIdx.x;
  const int seg = b >> 5, head = (b >> 3) & 3, ocg = b & 7;
  float acc[4] = {0.f, 0.f, 0.f, 0.f};
  for (int j = 0; j < 64; ++j) {
    const float* cp = ctx_p + (size_t)(seg*64 + j)*4096 + head*1024;
    #pragma unroll
    for (int e = 0; e < 4; ++e) acc[e] += cp[t + e*256];
  }
  if (t < 32) {
    float s = 0.f;
    for (int j = 0; j < 64; ++j) s += sume_p[(size_t)(seg*64 + j)*128 + head*32 + t];
    sse[t] = s;
  }
  #pragma unroll
  for (int e = 0; e < 4; ++e) sctx[t + e*256] = acc[e];
  __syncthreads();
  #pragma unroll
  for (int e = 0; e < 2; ++e) {
    int idx = t + e*256;              // 512 outputs: 32 kc x 16 oc
    int kc = idx >> 4, ocl = idx & 15;
    int oc = ocg*16 + ocl;
    float s = 0.f;
    #pragma unroll
    for (int vc = 0; vc < 32; ++vc)
      s += sctx[kc*32 + vc] * Wout[(head*32 + vc)*128 + oc];
    WcT[((size_t)seg*128 + oc)*128 + head*32 + kc] = f2bf(s / sse[kc]);
  }
}

// ---- q recompute -> softmax -> P LDS exchange -> out GEMM -> staged bf16 out store + stats2 partials
__global__ __launch_bounds__(256, 2) void k_out3(
    const unsigned short* __restrict__ xb, const unsigned short* __restrict__ WT,
    const float* __restrict__ Wqkv, const float* __restrict__ gn1w, const float* __restrict__ gn1b,
    const float* __restrict__ part, const unsigned short* __restrict__ WcT,
    float* __restrict__ part2, unsigned short* __restrict__ outm)
{
  __shared__ float sm[2];
  __shared__ float sb01[256];
  __shared__ float sbq[128];
  __shared__ float red[8];
  __shared__ __attribute__((aligned(16))) short pbuf[2][8 * 256];            // P exchange, dbuf
  __shared__ __attribute__((aligned(16))) unsigned short sou[2][16 * 272];   // out staging, dbuf

  const int t = threadIdx.x;
  const int w = t >> 6, lane = t & 63;
  const int lm = lane & 15, lg = lane >> 4;
  const int bid = blockIdx.x;               // 512 = 8 seg * 64 sub
  const int seg = bid >> 6;
  const size_t cb = (size_t)bid * 512;      // chunk point base

  // ---- prologue: stats1 -> rs; q-bias fold
  if (t < 64) {
    float s = part[(seg*64 + t)*2], q = part[(seg*64 + t)*2 + 1];
    #pragma unroll
    for (int o = 1; o < 64; o <<= 1) { s += __shfl_xor(s, o); q += __shfl_xor(q, o); }
    if (t == 0) {
      float mu = s * INVN;
      float var = q * INVN - mu * mu;
      float rs = rsqrtf(var + EPS_GN);
      sm[0] = mu * rs; sm[1] = rs;
    }
  }
  {
    int which = t >> 7, n = t & 127;
    const float* gv = which ? gn1w : gn1b;
    float s = 0.f;
    for (int ch = 0; ch < 128; ++ch) s += gv[ch] * Wqkv[ch*384 + n];
    sb01[t] = s;
  }
  __syncthreads();
  if (t < 128) sbq[t] = (sb01[t] - sm[0] * sb01[128 + t]) * QSCALE;
  __syncthreads();

  const float alq = sm[1] * QSCALE;
  const float4 cq0 = *(const float4*)&sbq[w*32 + lg*4];
  const float4 cq1 = *(const float4*)&sbq[w*32 + 16 + lg*4];

  // register-resident Wq frags (head w) and Wc frags (this wave's 32 oc)
  bf16x8 wq[2][4];
  #pragma unroll
  for (int nt = 0; nt < 2; ++nt)
    #pragma unroll
    for (int kk = 0; kk < 4; ++kk)
      wq[nt][kk] = *(const bf16x8*)&WT[(w*32 + nt*16 + lm) * 128 + kk*32 + lg*8];
  s16x4 wc[2][8];
  #pragma unroll
  for (int o = 0; o < 2; ++o)
    #pragma unroll
    for (int kt = 0; kt < 8; ++kt)
      wc[o][kt] = *(const s16x4*)&WcT[((size_t)seg*128 + (w*32 + o*16 + lm))*128 + kt*16 + lg*4];

  const unsigned short* xw = xb + (cb + lm) * 128 + lg*8;
  float ssum = 0.f, ssq = 0.f;

  #pragma unroll 1
  for (int ia = 0; ia < 32; ++ia) {
    const unsigned short* p_ = xw + (size_t)(ia * 16) * 128;
    bf16x8 xf0 = *(const bf16x8*)(p_);
    bf16x8 xf1 = *(const bf16x8*)(p_ + 32);
    bf16x8 xf2 = *(const bf16x8*)(p_ + 64);
    bf16x8 xf3 = *(const bf16x8*)(p_ + 96);
    f32x4 qa0 = {0,0,0,0}, qa1 = {0,0,0,0};
    qa0 = MFMA32(wq[0][0], xf0, qa0); qa1 = MFMA32(wq[1][0], xf0, qa1);
    qa0 = MFMA32(wq[0][1], xf1, qa0); qa1 = MFMA32(wq[1][1], xf1, qa1);
    qa0 = MFMA32(wq[0][2], xf2, qa0); qa1 = MFMA32(wq[1][2], xf2, qa1);
    qa0 = MFMA32(wq[0][3], xf3, qa0); qa1 = MFMA32(wq[1][3], xf3, qa1);
    float a[8];
    #pragma unroll
    for (int r = 0; r < 4; ++r) {
      a[r]     = fmaf(qa0[r], alq, ((const float*)&cq0)[r]);
      a[4 + r] = fmaf(qa1[r], alq, ((const float*)&cq1)[r]);
    }
    float m = a[0];
    #pragma unroll
    for (int i = 1; i < 8; ++i) m = fmaxf(m, a[i]);
    m = fmaxf(m, __shfl_xor(m, 16));
    m = fmaxf(m, __shfl_xor(m, 32));
    float s = 0.f;
    #pragma unroll
    for (int i = 0; i < 8; ++i) { a[i] = __expf(a[i] - m); s += a[i]; }
    s += __shfl_xor(s, 16);
    s += __shfl_xor(s, 32);
    float inv = 1.f / s;
    *(s16x4*)&pbuf[ia & 1][(w*2)*256 + lane*4]     = pack4(a[0]*inv, a[1]*inv, a[2]*inv, a[3]*inv);
    *(s16x4*)&pbuf[ia & 1][(w*2 + 1)*256 + lane*4] = pack4(a[4]*inv, a[5]*inv, a[6]*inv, a[7]*inv);
    __syncthreads();
    f32x4 acc0 = {0,0,0,0}, acc1 = {0,0,0,0};
    #pragma unroll
    for (int kt = 0; kt < 8; ++kt) {
      s16x4 pk = *(const s16x4*)&pbuf[ia & 1][kt*256 + lane*4];
      acc0 = MFMA16(wc[0][kt], pk, acc0);
      acc1 = MFMA16(wc[1][kt], pk, acc1);
    }
    #pragma unroll
    for (int r = 0; r < 4; ++r) {
      ssum += acc0[r] + acc1[r];
      ssq  += acc0[r]*acc0[r] + acc1[r]*acc1[r];
    }
    // stage this tile's out rows (point-major) and store linear
    {
      unsigned short* dst = &sou[ia & 1][lm*272 + w*32 + lg*4];
      dst[0] = f2bf(acc0[0]); dst[1] = f2bf(acc0[1]);
      dst[2] = f2bf(acc0[2]); dst[3] = f2bf(acc0[3]);
      dst += 16;
      dst[0] = f2bf(acc1[0]); dst[1] = f2bf(acc1[1]);
      dst[2] = f2bf(acc1[2]); dst[3] = f2bf(acc1[3]);
    }
    __syncthreads();
    #pragma unroll
    for (int j = 0; j < 2; ++j) {
      int f = t + j*256;
      int pt = f >> 5, cc = f & 31;
      ((ushort4*)outm)[(cb + (size_t)ia*16 + pt)*32 + cc] = *(const ushort4*)&sou[ia & 1][pt*272 + cc*4];
    }
  }

  #pragma unroll
  for (int o = 1; o < 64; o <<= 1) { ssum += __shfl_xor(ssum, o); ssq += __shfl_xor(ssq, o); }
  if (lane == 0) { red[w*2] = ssum; red[w*2+1] = ssq; }
  __syncthreads();
  if (t == 0) {
    part2[bid*2]   = red[0] + red[2] + red[4] + red[6];
    part2[bid*2+1] = red[1] + red[3] + red[5] + red[7];
  }
}

// ---- GN2 (stats from part2) + residual
__global__ __launch_bounds__(256) void k_fin(
    const unsigned short* __restrict__ xb, const unsigned short* __restrict__ out_ws,
    const float* __restrict__ part2, const float* __restrict__ gn2w, const float* __restrict__ gn2b,
    float* __restrict__ y)
{
  __shared__ float sm[2];
  const int t = threadIdx.x;
  const int b = blockIdx.x >> 8, blk = blockIdx.x & 255;
  if (t < 64) {
    float s = part2[(b*64 + t)*2], q = part2[(b*64 + t)*2 + 1];
    #pragma unroll
    for (int o = 1; o < 64; o <<= 1) { s += __shfl_xor(s, o); q += __shfl_xor(q, o); }
    if (t == 0) {
      float mu = s * INVN;
      float var = q * INVN - mu * mu;
      sm[0] = mu; sm[1] = rsqrtf(var + EPS_GN);
    }
  }
  __syncthreads();
  const float mu = sm[0], rs = sm[1];
  const int c4 = t & 31;
  const float4 w4 = *(const float4*)&gn2w[c4*4];
  const float4 g4 = *(const float4*)&gn2b[c4*4];
  const size_t base = (size_t)b * 1048576 + (size_t)blk * 4096;
  const ushort4* xp = (const ushort4*)xb + base;
  const ushort4* op = (const ushort4*)out_ws + base;
  float4* yp = (float4*)y + base;
  #pragma unroll
  for (int i = 0; i < 16; ++i) {
    int f = t + i * 256;
    ushort4 xv = xp[f];
    ushort4 ov = op[f];
    float4 r;
    r.x = (bf2f(ov.x) - mu) * rs * w4.x + g4.x + bf2f(xv.x);
    r.y = (bf2f(ov.y) - mu) * rs * w4.y + g4.y + bf2f(xv.y);
    r.z = (bf2f(ov.z) - mu) * rs * w4.z + g4.z + bf2f(xv.z);
    r.w = (bf2f(ov.w) - mu) * rs * w4.w + g4.w + bf2f(xv.w);
    yp[f] = r;
  }
}

extern "C" void kernel_launch(void* const* d_in, const int* in_sizes, int n_in,
                              void* d_out, int out_size, void* d_ws, size_t ws_size,
                              hipStream_t stream) {
  const float* x    = (const float*)d_in[0];
  const float* gn1w = (const float*)d_in[1];
  const float* gn1b = (const float*)d_in[2];
  const float* Wqkv = (const float*)d_in[3];
  const float* Wout = (const float*)d_in[4];
  const float* gn2w = (const float*)d_in[5];
  const float* gn2b = (const float*)d_in[6];
  float* y = (float*)d_out;
  char* ws = (char*)d_ws;

  float*          part   = (float*)(ws + 0);                 // 512*2 f32
  float*          part2  = (float*)(ws + 4096);              // 512*2 f32
  unsigned short* WT     = (unsigned short*)(ws + 8192);     // 384*128 bf16
  unsigned short* WcT    = (unsigned short*)(ws + 106496);   // 8*128*128 bf16 = 262144
  float*          sume_p = (float*)(ws + 368640);            // 512*128 f32 = 262144
  float*          ctx_p  = (float*)(ws + 630784);            // 512*4096 f32 = 8388608
  unsigned short* xb     = (unsigned short*)(ws + 9019392);  // 67108864
  unsigned short* outm   = (unsigned short*)(ws + 76128256); // 67108864

  hipLaunchKernelGGL(k_pre,  dim3(704),  dim3(256), 0, stream, x, part, xb, Wqkv, gn1w, WT);
  hipLaunchKernelGGL(k_kv,   dim3(512),  dim3(256), 0, stream, xb, WT, Wqkv, gn1w, gn1b, part, sume_p, ctx_p);
  hipLaunchKernelGGL(k_wc,   dim3(256),  dim3(256), 0, stream, sume_p, ctx_p, Wout, WcT);
  hipLaunchKernelGGL(k_out3, dim3(512),  dim3(256), 0, stream, xb, WT, Wqkv, gn1w, gn1b, part, WcT, part2, outm);
  hipLaunchKernelGGL(k_fin,  dim3(2048), dim3(256), 0, stream, xb, outm, part2, gn2w, gn2b, y);
}